// Round 13
// baseline (9120.798 us; speedup 1.0000x reference)
//
#include <hip/hip_runtime.h>

#define V 256
#define H 2048
#define A 512
#define S 512
#define NBLK 128
#define NPROD 32
#define NTHR 512
#define CH 64            // floats per h-chunk slot (256B spread)
#define HPH (512*CH)     // h-exchange floats per phase
#define PPH (128*128)    // pe-exchange floats per phase: 128 c-groups x 32 b x 4 floats
#define SENTU 0x7FC00000u

typedef float f32x4 __attribute__((ext_vector_type(4)));
typedef float f32x2 __attribute__((ext_vector_type(2)));
typedef unsigned long long u64;

// ---- plain coherent poll side ----
__device__ __forceinline__ f32x4 ld_cg4(const float* p) {
    f32x4 r;
    asm volatile("global_load_dwordx4 %0, %1, off sc0 sc1\n\ts_waitcnt vmcnt(0)"
                 : "=&v"(r) : "v"(p) : "memory");
    return r;
}
__device__ __forceinline__ f32x4 poll4(const float* p) {
    f32x4 r = ld_cg4(p);
    while (__float_as_uint(r.x) == SENTU || __float_as_uint(r.y) == SENTU ||
           __float_as_uint(r.z) == SENTU || __float_as_uint(r.w) == SENTU)
        r = ld_cg4(p);
    return r;
}
__device__ __forceinline__ bool anynan(f32x4 v) {
    return __float_as_uint(v.x) == SENTU || __float_as_uint(v.y) == SENTU ||
           __float_as_uint(v.z) == SENTU || __float_as_uint(v.w) == SENTU;
}
// batched poll of 8 contiguous 16B chunks (128B span) via offset immediates
__device__ __forceinline__ void poll8(const float* p, f32x4 o[8]) {
    for (;;) {
        f32x4 a0,a1,a2,a3,a4,a5,a6,a7;
        asm volatile(
            "global_load_dwordx4 %0, %8, off sc0 sc1\n\t"
            "global_load_dwordx4 %1, %8, off offset:16 sc0 sc1\n\t"
            "global_load_dwordx4 %2, %8, off offset:32 sc0 sc1\n\t"
            "global_load_dwordx4 %3, %8, off offset:48 sc0 sc1\n\t"
            "global_load_dwordx4 %4, %8, off offset:64 sc0 sc1\n\t"
            "global_load_dwordx4 %5, %8, off offset:80 sc0 sc1\n\t"
            "global_load_dwordx4 %6, %8, off offset:96 sc0 sc1\n\t"
            "global_load_dwordx4 %7, %8, off offset:112 sc0 sc1\n\t"
            "s_waitcnt vmcnt(0)"
            : "=&v"(a0),"=&v"(a1),"=&v"(a2),"=&v"(a3),
              "=&v"(a4),"=&v"(a5),"=&v"(a6),"=&v"(a7)
            : "v"(p) : "memory");
        if (!(anynan(a0)||anynan(a1)||anynan(a2)||anynan(a3)||
              anynan(a4)||anynan(a5)||anynan(a6)||anynan(a7))) {
            o[0]=a0;o[1]=a1;o[2]=a2;o[3]=a3;o[4]=a4;o[5]=a5;o[6]=a6;o[7]=a7;
            return;
        }
    }
}
// ---- publishes (drain prior resets, then write-through store) ----
__device__ __forceinline__ void st_pub2(float* p, float x, float y) {
    f32x2 v; v.x = x; v.y = y;
    asm volatile("s_waitcnt vmcnt(0)\n\tglobal_store_dwordx2 %0, %1, off sc0 sc1"
                 :: "v"(p), "v"(v) : "memory");
}
__device__ __forceinline__ void st_pub4(float* p, f32x4 v) {
    asm volatile("s_waitcnt vmcnt(0)\n\tglobal_store_dwordx4 %0, %1, off sc0 sc1"
                 :: "v"(p), "v"(v) : "memory");
}
// ---- atomic publish (enc h only) ----
__device__ __forceinline__ void vm_drain() { asm volatile("s_waitcnt vmcnt(0)" ::: "memory"); }
__device__ __forceinline__ void ax_st64(u64* p, u64 v) {
    (void)__hip_atomic_exchange(p, v, __ATOMIC_RELAXED, __HIP_MEMORY_SCOPE_AGENT);
}
__device__ __forceinline__ u64 pack2(float a, float b) {
    return ((u64)__float_as_uint(b) << 32) | (u64)__float_as_uint(a);
}
// ---- plain resets ----
__device__ __forceinline__ void st_rst2(float* p) {
    f32x2 v; v.x = __uint_as_float(SENTU); v.y = __uint_as_float(SENTU);
    asm volatile("global_store_dwordx2 %0, %1, off sc0 sc1" :: "v"(p), "v"(v) : "memory");
}
__device__ __forceinline__ void st_rst4(float* p) {
    f32x4 v; v.x = v.y = v.z = v.w = __uint_as_float(SENTU);
    asm volatile("global_store_dwordx4 %0, %1, off sc0 sc1" :: "v"(p), "v"(v) : "memory");
}

__global__ void init_ex(unsigned* p, int n) {
    int i = blockIdx.x * blockDim.x + threadIdx.x;
    if (i < n) p[i] = SENTU;
}

// ---------------- generic NT GEMM ----------------
__global__ __launch_bounds__(256) void gemm_nt(
    const float* __restrict__ Amat, int lda,
    const float* __restrict__ Bmat, int ldb,
    float* __restrict__ C, int ldc,
    const float* __restrict__ bias, int M, int N, int K)
{
    __shared__ float As[16][68];
    __shared__ float Bs[16][68];
    const int tid = threadIdx.x;
    const int tx = tid & 15;
    const int ty = tid >> 4;
    const int m0 = blockIdx.y * 64;
    const int n0 = blockIdx.x * 64;
    const int lr = tid >> 2;
    const int lk = (tid & 3) * 4;

    float acc[4][4] = {};
    for (int k0 = 0; k0 < K; k0 += 16) {
        float4 av = *(const float4*)(Amat + (size_t)(m0 + lr) * lda + k0 + lk);
        float4 bv = *(const float4*)(Bmat + (size_t)(n0 + lr) * ldb + k0 + lk);
        __syncthreads();
        As[lk+0][lr] = av.x; As[lk+1][lr] = av.y; As[lk+2][lr] = av.z; As[lk+3][lr] = av.w;
        Bs[lk+0][lr] = bv.x; Bs[lk+1][lr] = bv.y; Bs[lk+2][lr] = bv.z; Bs[lk+3][lr] = bv.w;
        __syncthreads();
        #pragma unroll
        for (int k = 0; k < 16; ++k) {
            float a4[4], b4[4];
            #pragma unroll
            for (int i = 0; i < 4; ++i) a4[i] = As[k][ty*4+i];
            #pragma unroll
            for (int j = 0; j < 4; ++j) b4[j] = Bs[k][tx*4+j];
            #pragma unroll
            for (int i = 0; i < 4; ++i)
                #pragma unroll
                for (int j = 0; j < 4; ++j) acc[i][j] += a4[i] * b4[j];
        }
    }
    #pragma unroll
    for (int i = 0; i < 4; ++i) {
        const int m = m0 + ty*4 + i;
        #pragma unroll
        for (int j = 0; j < 4; ++j) {
            const int n = n0 + tx*4 + j;
            float v = acc[i][j];
            if (bias) v += bias[n];
            C[(size_t)m * ldc + n] = v;
        }
    }
}

// ---------------- persistent encoder scan (R12: atomic publish + folded x) ----------------
__global__ __launch_bounds__(NTHR, 2) void enc_scan(
    const float* __restrict__ W_enc, const float* __restrict__ x_enc,
    const float* __restrict__ b_enc,
    float* __restrict__ states, float* __restrict__ hex)
{
    __shared__ __align__(16) float hs[2][H];
    __shared__ __align__(16) float xs[2][V];
    const int tid = threadIdx.x;
    const int wid = tid >> 6, lane = tid & 63;
    const int w   = blockIdx.x * 8 + wid;
    const int r0  = 2*w, r1 = r0 + 1;
    const int slot = (w >> 1)*CH + (w & 1)*2;

    f32x4 we0[8], we1[8];
    #pragma unroll
    for (int k = 0; k < 8; ++k) {
        we0[k] = *(const f32x4*)(W_enc + (size_t)r0*(V+H) + V + 4*(lane + 64*k));
        we1[k] = *(const f32x4*)(W_enc + (size_t)r1*(V+H) + V + 4*(lane + 64*k));
    }
    const f32x4 wx0 = *(const f32x4*)(W_enc + (size_t)r0*(V+H) + 4*lane);
    const f32x4 wx1 = *(const f32x4*)(W_enc + (size_t)r1*(V+H) + 4*lane);
    const float bb0 = b_enc[r0], bb1 = b_enc[r1];

    if (tid < 64) ((f32x4*)xs[0])[tid] = ((const f32x4*)x_enc)[tid];
    __syncthreads();
    {
        f32x4 xv = ((const f32x4*)xs[0])[lane];
        float a0 = wx0.x*xv.x + wx0.y*xv.y + wx0.z*xv.z + wx0.w*xv.w;
        float a1 = wx1.x*xv.x + wx1.y*xv.y + wx1.z*xv.z + wx1.w*xv.w;
        #pragma unroll
        for (int off = 32; off; off >>= 1) { a0 += __shfl_down(a0, off); a1 += __shfl_down(a1, off); }
        if (lane == 0) {
            float h0 = tanhf(a0 + bb0), h1 = tanhf(a1 + bb1);
            vm_drain();
            ax_st64((u64*)(hex + 0*HPH + slot), pack2(h0, h1));
            states[r0] = h0; states[r1] = h1;
        }
    }

    for (int t = 1; t < S; ++t) {
        if (tid < 64) ((f32x4*)xs[t&1])[tid] = ((const f32x4*)(x_enc + (size_t)t*V))[tid];
        ((f32x4*)hs[t&1])[tid] = poll4(hex + ((t-1)%3)*HPH + tid*CH);
        __syncthreads();
        if (lane == 0) st_rst2(hex + ((t+1)%3)*HPH + slot);

        f32x4 xv = ((const f32x4*)xs[t&1])[lane];
        float a0 = wx0.x*xv.x + wx0.y*xv.y + wx0.z*xv.z + wx0.w*xv.w;
        float a1 = wx1.x*xv.x + wx1.y*xv.y + wx1.z*xv.z + wx1.w*xv.w;
        const f32x4* h4 = (const f32x4*)hs[t&1];
        #pragma unroll
        for (int k = 0; k < 8; ++k) {
            f32x4 hv = h4[lane + 64*k];
            a0 += we0[k].x*hv.x + we0[k].y*hv.y + we0[k].z*hv.z + we0[k].w*hv.w;
            a1 += we1[k].x*hv.x + we1[k].y*hv.y + we1[k].z*hv.z + we1[k].w*hv.w;
        }
        #pragma unroll
        for (int off = 32; off; off >>= 1) { a0 += __shfl_down(a0, off); a1 += __shfl_down(a1, off); }
        if (lane == 0) {
            float h0 = tanhf(a0 + bb0), h1 = tanhf(a1 + bb1);
            vm_drain();
            ax_st64((u64*)(hex + (t%3)*HPH + slot), pack2(h0, h1));
            states[(size_t)t*H + r0] = h0;
            states[(size_t)t*H + r1] = h1;
        }
    }
}

// ---------------- persistent decoder scan: 2 hops/step via partial energies ----------------
__global__ __launch_bounds__(NTHR, 2) void dec_scan(
    const float* __restrict__ Wa_dec, const float* __restrict__ W_dec,
    const float* __restrict__ enc_proj, const float* __restrict__ v_a,
    const float* __restrict__ WcT, const float* __restrict__ x_dec,
    const float* __restrict__ b_dec,
    const float* __restrict__ enc_states, float* __restrict__ h_dec,
    float* __restrict__ hexd, float* __restrict__ peex)
{
    __shared__ __align__(16) float hs[2][H];      // 16 KB
    __shared__ __align__(16) float es[S];         // 2 KB
    __shared__ __align__(16) float xs[2][V];      // 2 KB
    __shared__ __align__(16) float epT[16][S];    // 32 KB (producers)
    __shared__ __align__(16) float pel[S];        // 2 KB
    __shared__ __align__(16) f32x4 pl[4][128];    // 8 KB
    __shared__ float dpl[16];
    __shared__ float vsm[16];
    __shared__ float zred[8];
    const int tid = threadIdx.x;
    const int wid = tid >> 6, lane = tid & 63;
    const int bid = blockIdx.x;
    const int w   = bid * 8 + wid;
    const int r0  = 2*w, r1 = r0 + 1;
    const int hslot = (w >> 1)*CH + (w & 1)*2;
    const bool prod = (bid < NPROD);
    const int abase = bid * 16;                   // producer's 16 a-rows

    // register-resident weights
    f32x4 wh0[8], wh1[8], wc0[2], wc1[2];
    #pragma unroll
    for (int k = 0; k < 8; ++k) {
        wh0[k] = *(const f32x4*)(W_dec + (size_t)r0*(V+2*H) + V + H + 4*(lane + 64*k));
        wh1[k] = *(const f32x4*)(W_dec + (size_t)r1*(V+2*H) + V + H + 4*(lane + 64*k));
    }
    #pragma unroll
    for (int k = 0; k < 2; ++k) {
        wc0[k] = *(const f32x4*)(WcT + (size_t)r0*S + 4*(lane + 64*k));
        wc1[k] = *(const f32x4*)(WcT + (size_t)r1*S + 4*(lane + 64*k));
    }
    const f32x4 wx0 = *(const f32x4*)(W_dec + (size_t)r0*(V+2*H) + 4*lane);
    const f32x4 wx1 = *(const f32x4*)(W_dec + (size_t)r1*(V+2*H) + 4*lane);
    const float bb0 = b_dec[r0], bb1 = b_dec[r1];

    // producer prologue: ep columns (transposed) + v_a slice
    if (prod) {
        #pragma unroll
        for (int al = 0; al < 16; ++al)
            epT[al][tid] = enc_proj[(size_t)tid*A + abase + al];
        if (tid < 16) vsm[tid] = v_a[abase + tid];
    }

    const f32x4* es4 = (const f32x4*)es;

    for (int t = 0; t < S; ++t) {
        const int ph  = t % 3;
        const int phn = (t+1) % 3;
        const int php = (t+2) % 3;   // == (t-1)%3

        if (tid < 64) ((f32x4*)xs[t&1])[tid] = ((const f32x4*)(x_dec + (size_t)t*V))[tid];

        // ---- A: stage h_{t-1} ----
        if (t == 0) ((f32x4*)hs[0])[tid] = ((const f32x4*)(enc_states + (size_t)(S-1)*H))[tid];
        else        ((f32x4*)hs[t&1])[tid] = poll4(hexd + php*HPH + tid*CH);
        __syncthreads();                                   // sync1 (also covers epT/vsm at t=0)

        // resets (proven-consumed phases; drain into next publish)
        if (lane == 0) st_rst2(hexd + phn*HPH + hslot);
        if (t > 0 && prod && tid < 128)
            st_rst4(peex + php*PPH + tid*128 + bid*4);

        const f32x4* h4 = (const f32x4*)hs[t&1];

        // ---- B: producers: dp (16 rows from L2 Wa) -> partial energies -> publish ----
        if (prod) {
            const size_t wbase = (size_t)(abase + 2*wid) * H;
            float d0 = 0.f, d1 = 0.f;
            #pragma unroll
            for (int k = 0; k < 8; ++k) {
                f32x4 a0 = *(const f32x4*)(Wa_dec + wbase + 4*(lane + 64*k));
                f32x4 a1 = *(const f32x4*)(Wa_dec + wbase + H + 4*(lane + 64*k));
                f32x4 hv = h4[lane + 64*k];
                d0 += a0.x*hv.x + a0.y*hv.y + a0.z*hv.z + a0.w*hv.w;
                d1 += a1.x*hv.x + a1.y*hv.y + a1.z*hv.z + a1.w*hv.w;
            }
            #pragma unroll
            for (int off = 32; off; off >>= 1) { d0 += __shfl_down(d0, off); d1 += __shfl_down(d1, off); }
            if (lane == 0) { dpl[2*wid] = d0; dpl[2*wid+1] = d1; }
            __syncthreads();                               // dpl ready (block-uniform branch)
            float pe = 0.f;
            #pragma unroll
            for (int al = 0; al < 16; ++al)
                pe += vsm[al] * tanhf(epT[al][tid] + dpl[al]);
            pel[tid] = pe;
            __syncthreads();                               // pel ready
            if (tid < 128) {
                f32x4 v = *(const f32x4*)(&pel[4*tid]);
                st_pub4(peex + ph*PPH + tid*128 + bid*4, v);
            }
        }

        // ---- W_h (+Wx) dots (all blocks; overlaps pe hop) ----
        f32x4 xv = ((const f32x4*)xs[t&1])[lane];
        float aH0 = wx0.x*xv.x + wx0.y*xv.y + wx0.z*xv.z + wx0.w*xv.w;
        float aH1 = wx1.x*xv.x + wx1.y*xv.y + wx1.z*xv.z + wx1.w*xv.w;
        #pragma unroll
        for (int k = 0; k < 8; ++k) {
            f32x4 hv = h4[lane + 64*k];
            aH0 += wh0[k].x*hv.x + wh0[k].y*hv.y + wh0[k].z*hv.z + wh0[k].w*hv.w;
            aH1 += wh1[k].x*hv.x + wh1[k].y*hv.y + wh1[k].z*hv.z + wh1[k].w*hv.w;
        }
        #pragma unroll
        for (int off = 32; off; off >>= 1) { aH0 += __shfl_down(aH0, off); aH1 += __shfl_down(aH1, off); }

        // ---- C: poll + reduce partial energies (one hop) ----
        {
            const int g = tid >> 7, c = tid & 127;
            f32x4 o[8];
            poll8(peex + ph*PPH + c*128 + g*32, o);
            pl[g][c] = (o[0]+o[1]) + (o[2]+o[3]) + ((o[4]+o[5]) + (o[6]+o[7]));
        }
        __syncthreads();                                   // pl ready
        if (tid < 128) {
            f32x4 tot = (pl[0][tid] + pl[1][tid]) + (pl[2][tid] + pl[3][tid]);
            es[4*tid+0] = expf(tot.x);
            es[4*tid+1] = expf(tot.y);
            es[4*tid+2] = expf(tot.z);
            es[4*tid+3] = expf(tot.w);
        }
        __syncthreads();                                   // es ready

        // ---- D: Z, ctx, h_new, publish ----
        float z = es[tid];
        #pragma unroll
        for (int off = 32; off; off >>= 1) z += __shfl_down(z, off);
        if (lane == 0) zred[wid] = z;
        __syncthreads();                                   // syncZ
        const float Z = zred[0]+zred[1]+zred[2]+zred[3]+zred[4]+zred[5]+zred[6]+zred[7];

        float c0 = 0.f, c1 = 0.f;
        #pragma unroll
        for (int k = 0; k < 2; ++k) {
            f32x4 ev = es4[lane + 64*k];
            c0 += wc0[k].x*ev.x + wc0[k].y*ev.y + wc0[k].z*ev.z + wc0[k].w*ev.w;
            c1 += wc1[k].x*ev.x + wc1[k].y*ev.y + wc1[k].z*ev.z + wc1[k].w*ev.w;
        }
        #pragma unroll
        for (int off = 32; off; off >>= 1) { c0 += __shfl_down(c0, off); c1 += __shfl_down(c1, off); }

        if (lane == 0) {
            const float Zi = 1.f / Z;
            float h0 = tanhf(aH0 + bb0 + c0*Zi);
            float h1 = tanhf(aH1 + bb1 + c1*Zi);
            st_pub2(hexd + ph*HPH + hslot, h0, h1);        // vmcnt drain orders resets
            f32x2 hv; hv.x = h0; hv.y = h1;                // off critical path
            *(f32x2*)(h_dec + (size_t)t*H + r0) = hv;
        }
    }
}

extern "C" void kernel_launch(void* const* d_in, const int* in_sizes, int n_in,
                              void* d_out, int out_size, void* d_ws, size_t ws_size,
                              hipStream_t stream) {
    const float* x_enc  = (const float*)d_in[0];
    const float* x_dec  = (const float*)d_in[1];
    const float* W_enc  = (const float*)d_in[2];
    const float* b_enc  = (const float*)d_in[3];
    const float* Wa_enc = (const float*)d_in[4];
    const float* Wa_dec = (const float*)d_in[5];
    const float* v_a    = (const float*)d_in[6];
    const float* W_dec  = (const float*)d_in[7];
    const float* b_dec  = (const float*)d_in[8];
    const float* W_out  = (const float*)d_in[9];
    const float* b_out  = (const float*)d_in[10];
    float* out = (float*)d_out;

    float* ws         = (float*)d_ws;
    float* enc_states = ws;                          // S*H
    float* enc_proj   = enc_states + (size_t)S*H;    // S*A
    float* WcT        = enc_proj + (size_t)S*A;      // H*S
    float* h_dec      = WcT + (size_t)H*S;           // S*H
    float* hex_e      = h_dec + (size_t)S*H;         // 3*HPH
    float* hex_d      = hex_e + 3*HPH;               // 3*HPH
    float* pe_ex      = hex_d + 3*HPH;               // 3*PPH
    const int n_ex = 3*HPH*2 + 3*PPH;

    dim3 b256(256);

    init_ex<<<dim3((n_ex + 255)/256), b256, 0, stream>>>((unsigned*)hex_e, n_ex);

    // encoder scan (x-projection folded; no accx GEMM)
    {
        const float* We = W_enc; const float* xe = x_enc; const float* be = b_enc;
        float* st = enc_states; float* hx = hex_e;
        void* args[] = { &We, &xe, &be, &st, &hx };
        hipLaunchCooperativeKernel((void*)enc_scan, dim3(NBLK), dim3(NTHR), args, 0, stream);
    }

    // enc_proj = enc_states @ Wa_enc.T
    gemm_nt<<<dim3(A/64, S/64), b256, 0, stream>>>(enc_states, H, Wa_enc, H, enc_proj, A, nullptr, S, A, H);
    // WcT[i][s] = W_c[i]·enc_states[s]
    gemm_nt<<<dim3(S/64, H/64), b256, 0, stream>>>(W_dec + V, V+2*H, enc_states, H, WcT, S, nullptr, H, S, H);

    // decoder scan (2 hops/step: h + partial-energy)
    {
        const float* wa = Wa_dec; const float* wd = W_dec; const float* epj = enc_proj;
        const float* vv = v_a; const float* wc = WcT; const float* xd = x_dec;
        const float* bd = b_dec; const float* est = enc_states; float* hd = h_dec;
        float* hx = hex_d; float* px = pe_ex;
        void* args[] = { &wa, &wd, &epj, &vv, &wc, &xd, &bd, &est, &hd, &hx, &px };
        hipLaunchCooperativeKernel((void*)dec_scan, dim3(NBLK), dim3(NTHR), args, 0, stream);
    }

    // logits = h_dec @ W_out.T + b_out
    gemm_nt<<<dim3(V/64, S/64), b256, 0, stream>>>(h_dec, H, W_out, H, out, V, b_out, S, V, H);
}